// Round 14
// baseline (141.163 us; speedup 1.0000x reference)
//
#include <hip/hip_runtime.h>

#define BT_ROWS 65536
#define DIM     512
#define NK      32
#define TPB     256                    // 4 waves; each wave = one D-quarter of the 32-row tile
#define RPB     32                     // 32 rows = one 32x32x16 MFMA M-tile
#define NBLK    (BT_ROWS / RPB)        // 2048 blocks -> 8 blocks/CU, 32 waves/CU
#define CHUNK   32                     // dims per chunk (128B/row)
#define NCW     4                      // chunks per wave (128 dims)
#define DQ      3                      // register flight depth

typedef float f4 __attribute__((ext_vector_type(4)));
typedef float f32x16 __attribute__((ext_vector_type(16)));
typedef short bf16x8 __attribute__((ext_vector_type(8)));
typedef unsigned int u32x4 __attribute__((ext_vector_type(4)));

union Frag { u32x4 q; unsigned int w[4]; bf16x8 v; };

// d_ws: float c2[32] | float blockloss[2048] | int counts[32] | ... | u32 cbh[8192] @ byte 16384

__global__ void vq_prep(const float* __restrict__ cb, float* __restrict__ c2,
                        int* __restrict__ counts, unsigned int* __restrict__ cbh32) {
    int t = threadIdx.x;               // 256 threads
    const f4* c4 = (const f4*)cb;
#pragma unroll
    for (int i = 0; i < 16; ++i) {
        f4 v = c4[t * 16 + i];
        unsigned int w0, w1;
        asm("v_cvt_pk_bf16_f32 %0, %1, %2" : "=v"(w0) : "v"(v.x), "v"(v.y));
        asm("v_cvt_pk_bf16_f32 %0, %1, %2" : "=v"(w1) : "v"(v.z), "v"(v.w));
        cbh32[t * 32 + 2 * i]     = w0;
        cbh32[t * 32 + 2 * i + 1] = w1;
    }
    if (t < NK) {
        float s = 0.f;
#pragma unroll 8
        for (int i = 0; i < DIM / 4; ++i) {
            f4 v = c4[t * (DIM / 4) + i];
            s += v.x * v.x + v.y * v.y + v.z * v.z + v.w * v.w;
        }
        c2[t] = s;
    } else if (t < 2 * NK) {
        counts[t - NK] = 0;
    }
}

__global__ __launch_bounds__(TPB, 8) void vq_main(const float* __restrict__ x,
                                                  const float* __restrict__ cb,
                                                  const float* __restrict__ c2,
                                                  const unsigned short* __restrict__ cbh,
                                                  float* __restrict__ out,
                                                  float* __restrict__ blockloss,
                                                  int* __restrict__ counts) {
    const int tid  = threadIdx.x;
    const int lane = tid & 63;
    const int wv   = tid >> 6;             // wave 0..3: D-quarter [wv*128, wv*128+128)
    const int n    = lane & 31;            // A-row within tile AND B-concept column
    const int hi   = lane >> 5;            // k-half selector within each 16-k MFMA step
    const int R0   = blockIdx.x * RPB;

    __shared__ float         comb[3][17][64];   // waves 1-3: acc[16] + x2 partials
    __shared__ unsigned char karr[RPB];

    // Direct global->reg A-path (R12-verified pattern), shifted by wv*128 dims.
    // D-quarter byte offset: wv * NCW chunks * 128B = wv * 512B  (R13 bug: was wv*2048B -> OOB fault)
    const char* xb = (const char*)x + (size_t)(R0 + n) * (DIM * 4) + wv * (NCW * CHUNK * 4) + hi * 32;
    const unsigned short* cbn = cbh + (size_t)n * DIM + wv * (CHUNK * NCW) + hi * 8;

    f4   rs[DQ][4];                        // x flight
    Frag fr[DQ][2];                        // cb flight
#define GLOAD(c) do {                                                    \
    rs[(c) % DQ][0] = *(const f4*)(xb + (c) * 128);                      \
    rs[(c) % DQ][1] = *(const f4*)(xb + (c) * 128 + 16);                 \
    rs[(c) % DQ][2] = *(const f4*)(xb + (c) * 128 + 64);                 \
    rs[(c) % DQ][3] = *(const f4*)(xb + (c) * 128 + 80);                 \
    fr[(c) % DQ][0].q = *(const u32x4*)(cbn + (c) * CHUNK);              \
    fr[(c) % DQ][1].q = *(const u32x4*)(cbn + (c) * CHUNK + 16);         \
} while (0)

    f32x16 acc;
#pragma unroll
    for (int r = 0; r < 16; ++r) acc[r] = 0.f;
    float x2acc = 0.f;

    GLOAD(0); GLOAD(1); GLOAD(2);

#pragma unroll
    for (int c = 0; c < NCW; ++c) {
        f4   a0 = rs[c % DQ][0], a1 = rs[c % DQ][1];
        f4   a2 = rs[c % DQ][2], a3 = rs[c % DQ][3];
        Frag f0 = fr[c % DQ][0], f1 = fr[c % DQ][1];
        if (c + DQ < NCW) GLOAD(c + DQ);

        x2acc += a0.x * a0.x + a0.y * a0.y + a0.z * a0.z + a0.w * a0.w
               + a1.x * a1.x + a1.y * a1.y + a1.z * a1.z + a1.w * a1.w
               + a2.x * a2.x + a2.y * a2.y + a2.z * a2.z + a2.w * a2.w
               + a3.x * a3.x + a3.y * a3.y + a3.z * a3.z + a3.w * a3.w;

        Frag fa;
        asm("v_cvt_pk_bf16_f32 %0, %1, %2" : "=v"(fa.w[0]) : "v"(a0.x), "v"(a0.y));
        asm("v_cvt_pk_bf16_f32 %0, %1, %2" : "=v"(fa.w[1]) : "v"(a0.z), "v"(a0.w));
        asm("v_cvt_pk_bf16_f32 %0, %1, %2" : "=v"(fa.w[2]) : "v"(a1.x), "v"(a1.y));
        asm("v_cvt_pk_bf16_f32 %0, %1, %2" : "=v"(fa.w[3]) : "v"(a1.z), "v"(a1.w));
        acc = __builtin_amdgcn_mfma_f32_32x32x16_bf16(fa.v, f0.v, acc, 0, 0, 0);

        Frag fb;
        asm("v_cvt_pk_bf16_f32 %0, %1, %2" : "=v"(fb.w[0]) : "v"(a2.x), "v"(a2.y));
        asm("v_cvt_pk_bf16_f32 %0, %1, %2" : "=v"(fb.w[1]) : "v"(a2.z), "v"(a2.w));
        asm("v_cvt_pk_bf16_f32 %0, %1, %2" : "=v"(fb.w[2]) : "v"(a3.x), "v"(a3.y));
        asm("v_cvt_pk_bf16_f32 %0, %1, %2" : "=v"(fb.w[3]) : "v"(a3.z), "v"(a3.w));
        acc = __builtin_amdgcn_mfma_f32_32x32x16_bf16(fb.v, f1.v, acc, 0, 0, 0);
    }
#undef GLOAD

    // ---- D-combine: waves 1-3 publish partials; wave 0 reduces (plain LDS dataflow)
    if (wv > 0) {
#pragma unroll
        for (int r = 0; r < 16; ++r) comb[wv - 1][r][lane] = acc[r];
        comb[wv - 1][16][lane] = x2acc;
    }
    __syncthreads();

    if (wv == 0) {
#pragma unroll
        for (int w2 = 0; w2 < 3; ++w2) {
#pragma unroll
            for (int r = 0; r < 16; ++r) acc[r] += comb[w2][r][lane];
            x2acc += comb[w2][16][lane];
        }

        // R12-verified epilogue: x2 total, per-reg argmin butterfly, loss, hist
        float x2tot = x2acc;
#pragma unroll
        for (int mo = 1; mo <= 32; mo <<= 1) x2tot += __shfl_xor(x2tot, mo, 64);

        const float c2v = c2[n];
        float val[16]; int idx[16];
#pragma unroll
        for (int r = 0; r < 16; ++r) {
            val[r] = c2v - 2.f * acc[r];
            idx[r] = n;
#pragma unroll
            for (int off = 1; off <= 16; off <<= 1) {
                float ov = __shfl_xor(val[r], off, 64);
                int   oi = __shfl_xor(idx[r], off, 64);
                if (ov < val[r] || (ov == val[r] && oi < idx[r])) { val[r] = ov; idx[r] = oi; }
            }
        }

        float lsum = 0.f;
#pragma unroll
        for (int r = 0; r < 16; ++r) lsum += val[r];
        float lother = __shfl(lsum, 32, 64);
        if (lane == 0) blockloss[blockIdx.x] = x2tot + lsum + lother;

        int cnt = 0;
#pragma unroll
        for (int rr = 0; rr < 32; ++rr) {
            const int r = (rr & 3) | (((rr >> 3) & 3) << 2);
            const int h = (rr >> 2) & 1;
            int kr = __shfl(idx[r], h << 5, 64);        // uniform across wave
            cnt += (kr == n) ? 1 : 0;
            if (lane == 0) karr[rr] = (unsigned char)kr;
        }
        if (hi == 0 && cnt) atomicAdd(&counts[n], cnt);
    }
    __syncthreads();

    // q-store: all 4 waves, 8 rows each, 1KB contiguous per instruction (proven shape)
    const f4* __restrict__ cb4 = (const f4*)cb;
    f4* __restrict__ o4 = (f4*)out;
#pragma unroll 1
    for (int rr2 = 0; rr2 < 8; ++rr2) {
        const int rr = wv * 8 + rr2;
        int    kr   = karr[rr];                         // LDS broadcast, wave-uniform
        size_t base = (size_t)(R0 + rr) * (DIM / 4);
        o4[base + lane]      = cb4[kr * (DIM / 4) + lane];
        o4[base + 64 + lane] = cb4[kr * (DIM / 4) + 64 + lane];
    }
}

__global__ void vq_final(const float* __restrict__ blockloss, const int* __restrict__ counts,
                         float* __restrict__ out) {
    int   t = threadIdx.x;      // 256 threads, NBLK = 2048
    float v = 0.f;
#pragma unroll
    for (int i = 0; i < NBLK / 256; ++i) v += blockloss[t + i * 256];
#pragma unroll
    for (int m = 32; m; m >>= 1) v += __shfl_xor(v, m, 64);
    __shared__ float red[4];
    if ((t & 63) == 0) red[t >> 6] = v;
    __syncthreads();
    if (t == 0)
        out[(size_t)BT_ROWS * DIM] =
            1.25f * (red[0] + red[1] + red[2] + red[3]) / (float)((size_t)BT_ROWS * DIM);
    if (t < NK)
        out[(size_t)BT_ROWS * DIM + 1 + t] = (float)counts[t];
}

extern "C" void kernel_launch(void* const* d_in, const int* in_sizes, int n_in,
                              void* d_out, int out_size, void* d_ws, size_t ws_size,
                              hipStream_t stream) {
    const float* x  = (const float*)d_in[0];
    const float* cb = (const float*)d_in[1];
    float* out = (float*)d_out;

    float* f         = (float*)d_ws;
    float* c2        = f;
    float* blockloss = f + NK;
    int*   counts    = (int*)(f + NK + NBLK);
    unsigned int*   cbh32 = (unsigned int*)((char*)d_ws + 16384);
    unsigned short* cbh   = (unsigned short*)cbh32;

    vq_prep<<<1, 256, 0, stream>>>(cb, c2, counts, cbh32);
    vq_main<<<NBLK, TPB, 0, stream>>>(x, cb, c2, cbh, out, blockloss, counts);
    vq_final<<<1, 256, 0, stream>>>(blockloss, counts, out);
}

// Round 15
// 72.610 us; speedup vs baseline: 1.9441x; 1.9441x over previous
//
#include <hip/hip_runtime.h>

#define BT_ROWS 65536
#define DIM     512
#define NK      32
#define TPB     128                    // 2 waves; each wave = one D-half of the 32-row tile
#define RPB     32                     // 32 rows = one 32x32x16 MFMA M-tile
#define NBLK    (BT_ROWS / RPB)        // 2048 blocks -> 8 blocks/CU, 16 waves/CU
#define CHUNK   32                     // dims per chunk (128B/row)
#define NCW     8                      // chunks per wave (256 dims)
#define DQ      2                      // register flight depth (fits VGPR<=128, no spill)

typedef float f4 __attribute__((ext_vector_type(4)));
typedef float f32x16 __attribute__((ext_vector_type(16)));
typedef short bf16x8 __attribute__((ext_vector_type(8)));
typedef unsigned int u32x4 __attribute__((ext_vector_type(4)));

union Frag { u32x4 q; unsigned int w[4]; bf16x8 v; };

// d_ws: float c2[32] | float blockloss[2048] | int counts[32] | ... | u32 cbh[8192] @ byte 16384

__global__ void vq_prep(const float* __restrict__ cb, float* __restrict__ c2,
                        int* __restrict__ counts, unsigned int* __restrict__ cbh32) {
    int t = threadIdx.x;               // 256 threads
    const f4* c4 = (const f4*)cb;
#pragma unroll
    for (int i = 0; i < 16; ++i) {
        f4 v = c4[t * 16 + i];
        unsigned int w0, w1;
        asm("v_cvt_pk_bf16_f32 %0, %1, %2" : "=v"(w0) : "v"(v.x), "v"(v.y));
        asm("v_cvt_pk_bf16_f32 %0, %1, %2" : "=v"(w1) : "v"(v.z), "v"(v.w));
        cbh32[t * 32 + 2 * i]     = w0;
        cbh32[t * 32 + 2 * i + 1] = w1;
    }
    if (t < NK) {
        float s = 0.f;
#pragma unroll 8
        for (int i = 0; i < DIM / 4; ++i) {
            f4 v = c4[t * (DIM / 4) + i];
            s += v.x * v.x + v.y * v.y + v.z * v.z + v.w * v.w;
        }
        c2[t] = s;
    } else if (t < 2 * NK) {
        counts[t - NK] = 0;
    }
}

__global__ __launch_bounds__(TPB, 4) void vq_main(const float* __restrict__ x,
                                                  const float* __restrict__ cb,
                                                  const float* __restrict__ c2,
                                                  const unsigned short* __restrict__ cbh,
                                                  float* __restrict__ out,
                                                  float* __restrict__ blockloss,
                                                  int* __restrict__ counts) {
    const int tid  = threadIdx.x;
    const int lane = tid & 63;
    const int wv   = tid >> 6;             // wave 0..1: D-half [wv*256, wv*256+256)
    const int n    = lane & 31;            // A-row within tile AND B-concept column
    const int hi   = lane >> 5;            // k-half selector within each 16-k MFMA step
    const int R0   = blockIdx.x * RPB;

    __shared__ float         comb[17][64];      // wave 1: acc[16] + x2 partials
    __shared__ unsigned char karr[RPB];

    // Direct global->reg A-path (R12-verified pattern), shifted by wv*256 dims = wv*1024B.
    const char* xb = (const char*)x + (size_t)(R0 + n) * (DIM * 4) + wv * (NCW * CHUNK * 4) + hi * 32;
    const unsigned short* cbn = cbh + (size_t)n * DIM + wv * (CHUNK * NCW) + hi * 8;

    f4   rs[DQ][4];                        // x flight
    Frag fr[DQ][2];                        // cb flight
#define GLOAD(c) do {                                                    \
    rs[(c) % DQ][0] = *(const f4*)(xb + (c) * 128);                      \
    rs[(c) % DQ][1] = *(const f4*)(xb + (c) * 128 + 16);                 \
    rs[(c) % DQ][2] = *(const f4*)(xb + (c) * 128 + 64);                 \
    rs[(c) % DQ][3] = *(const f4*)(xb + (c) * 128 + 80);                 \
    fr[(c) % DQ][0].q = *(const u32x4*)(cbn + (c) * CHUNK);              \
    fr[(c) % DQ][1].q = *(const u32x4*)(cbn + (c) * CHUNK + 16);         \
} while (0)

    f32x16 acc;
#pragma unroll
    for (int r = 0; r < 16; ++r) acc[r] = 0.f;
    float x2acc = 0.f;

    GLOAD(0); GLOAD(1);

#pragma unroll
    for (int c = 0; c < NCW; ++c) {
        f4   a0 = rs[c % DQ][0], a1 = rs[c % DQ][1];
        f4   a2 = rs[c % DQ][2], a3 = rs[c % DQ][3];
        Frag f0 = fr[c % DQ][0], f1 = fr[c % DQ][1];
        if (c + DQ < NCW) GLOAD(c + DQ);

        x2acc += a0.x * a0.x + a0.y * a0.y + a0.z * a0.z + a0.w * a0.w
               + a1.x * a1.x + a1.y * a1.y + a1.z * a1.z + a1.w * a1.w
               + a2.x * a2.x + a2.y * a2.y + a2.z * a2.z + a2.w * a2.w
               + a3.x * a3.x + a3.y * a3.y + a3.z * a3.z + a3.w * a3.w;

        Frag fa;
        asm("v_cvt_pk_bf16_f32 %0, %1, %2" : "=v"(fa.w[0]) : "v"(a0.x), "v"(a0.y));
        asm("v_cvt_pk_bf16_f32 %0, %1, %2" : "=v"(fa.w[1]) : "v"(a0.z), "v"(a0.w));
        asm("v_cvt_pk_bf16_f32 %0, %1, %2" : "=v"(fa.w[2]) : "v"(a1.x), "v"(a1.y));
        asm("v_cvt_pk_bf16_f32 %0, %1, %2" : "=v"(fa.w[3]) : "v"(a1.z), "v"(a1.w));
        acc = __builtin_amdgcn_mfma_f32_32x32x16_bf16(fa.v, f0.v, acc, 0, 0, 0);

        Frag fb;
        asm("v_cvt_pk_bf16_f32 %0, %1, %2" : "=v"(fb.w[0]) : "v"(a2.x), "v"(a2.y));
        asm("v_cvt_pk_bf16_f32 %0, %1, %2" : "=v"(fb.w[1]) : "v"(a2.z), "v"(a2.w));
        asm("v_cvt_pk_bf16_f32 %0, %1, %2" : "=v"(fb.w[2]) : "v"(a3.x), "v"(a3.y));
        asm("v_cvt_pk_bf16_f32 %0, %1, %2" : "=v"(fb.w[3]) : "v"(a3.z), "v"(a3.w));
        acc = __builtin_amdgcn_mfma_f32_32x32x16_bf16(fb.v, f1.v, acc, 0, 0, 0);
    }
#undef GLOAD

    // ---- D-combine: wave 1 publishes partials; wave 0 reduces (plain LDS dataflow)
    if (wv == 1) {
#pragma unroll
        for (int r = 0; r < 16; ++r) comb[r][lane] = acc[r];
        comb[16][lane] = x2acc;
    }
    __syncthreads();

    if (wv == 0) {
#pragma unroll
        for (int r = 0; r < 16; ++r) acc[r] += comb[r][lane];
        x2acc += comb[16][lane];

        // R12-verified epilogue: x2 total, per-reg argmin butterfly, loss, hist
        float x2tot = x2acc;
#pragma unroll
        for (int mo = 1; mo <= 32; mo <<= 1) x2tot += __shfl_xor(x2tot, mo, 64);

        const float c2v = c2[n];
        float val[16]; int idx[16];
#pragma unroll
        for (int r = 0; r < 16; ++r) {
            val[r] = c2v - 2.f * acc[r];
            idx[r] = n;
#pragma unroll
            for (int off = 1; off <= 16; off <<= 1) {
                float ov = __shfl_xor(val[r], off, 64);
                int   oi = __shfl_xor(idx[r], off, 64);
                if (ov < val[r] || (ov == val[r] && oi < idx[r])) { val[r] = ov; idx[r] = oi; }
            }
        }

        float lsum = 0.f;
#pragma unroll
        for (int r = 0; r < 16; ++r) lsum += val[r];
        float lother = __shfl(lsum, 32, 64);
        if (lane == 0) blockloss[blockIdx.x] = x2tot + lsum + lother;

        int cnt = 0;
#pragma unroll
        for (int rr = 0; rr < 32; ++rr) {
            const int r = (rr & 3) | (((rr >> 3) & 3) << 2);
            const int h = (rr >> 2) & 1;
            int kr = __shfl(idx[r], h << 5, 64);        // uniform across wave
            cnt += (kr == n) ? 1 : 0;
            if (lane == 0) karr[rr] = (unsigned char)kr;
        }
        if (hi == 0 && cnt) atomicAdd(&counts[n], cnt);
    }
    __syncthreads();

    // q-store: both waves, 16 rows each, 1KB contiguous per instruction (proven shape)
    const f4* __restrict__ cb4 = (const f4*)cb;
    f4* __restrict__ o4 = (f4*)out;
#pragma unroll 1
    for (int rr2 = 0; rr2 < 16; ++rr2) {
        const int rr = wv * 16 + rr2;
        int    kr   = karr[rr];                         // LDS broadcast, wave-uniform
        size_t base = (size_t)(R0 + rr) * (DIM / 4);
        o4[base + lane]      = cb4[kr * (DIM / 4) + lane];
        o4[base + 64 + lane] = cb4[kr * (DIM / 4) + 64 + lane];
    }
}

__global__ void vq_final(const float* __restrict__ blockloss, const int* __restrict__ counts,
                         float* __restrict__ out) {
    int   t = threadIdx.x;      // 256 threads, NBLK = 2048
    float v = 0.f;
#pragma unroll
    for (int i = 0; i < NBLK / 256; ++i) v += blockloss[t + i * 256];
#pragma unroll
    for (int m = 32; m; m >>= 1) v += __shfl_xor(v, m, 64);
    __shared__ float red[4];
    if ((t & 63) == 0) red[t >> 6] = v;
    __syncthreads();
    if (t == 0)
        out[(size_t)BT_ROWS * DIM] =
            1.25f * (red[0] + red[1] + red[2] + red[3]) / (float)((size_t)BT_ROWS * DIM);
    if (t < NK)
        out[(size_t)BT_ROWS * DIM + 1 + t] = (float)counts[t];
}

extern "C" void kernel_launch(void* const* d_in, const int* in_sizes, int n_in,
                              void* d_out, int out_size, void* d_ws, size_t ws_size,
                              hipStream_t stream) {
    const float* x  = (const float*)d_in[0];
    const float* cb = (const float*)d_in[1];
    float* out = (float*)d_out;

    float* f         = (float*)d_ws;
    float* c2        = f;
    float* blockloss = f + NK;
    int*   counts    = (int*)(f + NK + NBLK);
    unsigned int*   cbh32 = (unsigned int*)((char*)d_ws + 16384);
    unsigned short* cbh   = (unsigned short*)cbh32;

    vq_prep<<<1, 256, 0, stream>>>(cb, c2, counts, cbh32);
    vq_main<<<NBLK, TPB, 0, stream>>>(x, cb, c2, cbh, out, blockloss, counts);
    vq_final<<<1, 256, 0, stream>>>(blockloss, counts, out);
}